// Round 15
// baseline (1064.909 us; speedup 1.0000x reference)
//
#include <hip/hip_runtime.h>
#include <hip/hip_bf16.h>
#include <stdint.h>

#define BNUM 8
#define PNUM 2048
#define KNN  30
#define KSEL 40      // rank threshold for candidate selection
#define KCAP 64      // max candidates per row (one wave in refine)
#define NPT  (BNUM*PNUM)   // 16384
#define EPSF 1e-5f

typedef unsigned long long u64;
typedef unsigned short ushort_t;
typedef __attribute__((ext_vector_type(8))) short short8v;   // 8 bf16 (4 VGPRs)
typedef __attribute__((ext_vector_type(4))) float f32x4;

__device__ __forceinline__ unsigned mono_key(float d) {
    unsigned u = __float_as_uint(d);
    return (u & 0x80000000u) ? ~u : (u | 0x80000000u);   // monotone float->uint
}

__device__ __forceinline__ unsigned f2bf(float f) {      // f32 -> bf16 bits, RNE
    unsigned u = __float_as_uint(f);
    u += 0x7fffu + ((u >> 16) & 1u);
    return u >> 16;
}

__device__ __forceinline__ double lane_bcast64(double x, int l) {   // uniform l -> v_readlane
    union { double d; int i[2]; } a; a.d = x;
    union { int i[2]; double d; } r;
    r.i[0] = __builtin_amdgcn_readlane(a.i[0], l);
    r.i[1] = __builtin_amdgcn_readlane(a.i[1], l);
    return r.d;
}

// ---------- f0 = concat(x, pos) ----------
__global__ void k_concat6(const float* __restrict__ x, const float* __restrict__ pos,
                          float* __restrict__ f0) {
    int i = blockIdx.x*256 + threadIdx.x;        // < N*6
    int n = i/6, c = i%6;
    f0[i] = (c < 3) ? x[n*3 + c] : pos[n*3 + c - 3];
}

// ---------- s[n] = sum_c F[n][c]^2 ----------
template<int C>
__global__ void k_snorm(const float* __restrict__ F, float* __restrict__ s) {
    int n = blockIdx.x*256 + threadIdx.x;
    float a = 0.f;
    for (int c = 0; c < C; c++) { float t = F[(size_t)n*C + c]; a = fmaf(t, t, a); }
    s[n] = a;
}

// ---------- f32 dist (C=6 only): 128x128 tile, snorm fused ----------
template<int C>
__global__ __launch_bounds__(256) void k_dist(const float* __restrict__ F,
                                              ushort_t* __restrict__ Dk) {
    __shared__ float FpT[C][132];
    __shared__ float FqT[C][132];
    __shared__ float sp[128], sq[128];
    int b = blockIdx.z;
    int p0 = blockIdx.x*128, q0 = blockIdx.y*128;
    int t = threadIdx.x;
    for (int e = t; e < 128*C; e += 256) {
        int r = e / C, c = e % C;
        FpT[c][r] = F[(size_t)(b*PNUM + p0 + r)*C + c];
        FqT[c][r] = F[(size_t)(b*PNUM + q0 + r)*C + c];
    }
    __syncthreads();
    if (t < 128) {
        float a = 0.f;
        for (int c = 0; c < C; c++) { float xv = FpT[c][t]; a = fmaf(xv, xv, a); }
        sp[t] = a;
    } else {
        int r = t - 128;
        float a = 0.f;
        for (int c = 0; c < C; c++) { float xv = FqT[c][r]; a = fmaf(xv, xv, a); }
        sq[r] = a;
    }
    __syncthreads();
    int tc = (t & 15)*8, tr = (t >> 4)*8;
    float acc[8][8] = {};
    for (int c = 0; c < C; c++) {
        float4 p0v = *(const float4*)&FpT[c][tr];
        float4 p1v = *(const float4*)&FpT[c][tr+4];
        float4 q0v = *(const float4*)&FqT[c][tc];
        float4 q1v = *(const float4*)&FqT[c][tc+4];
        float av[8] = {p0v.x,p0v.y,p0v.z,p0v.w,p1v.x,p1v.y,p1v.z,p1v.w};
        float bv[8] = {q0v.x,q0v.y,q0v.z,q0v.w,q1v.x,q1v.y,q1v.z,q1v.w};
        #pragma unroll
        for (int i = 0; i < 8; i++)
            #pragma unroll
            for (int j = 0; j < 8; j++) acc[i][j] = fmaf(av[i], bv[j], acc[i][j]);
    }
    #pragma unroll
    for (int i = 0; i < 8; i++) {
        unsigned ks[8];
        #pragma unroll
        for (int j = 0; j < 8; j++) {
            float d = sp[tr + i] + sq[tc + j] - 2.0f*acc[i][j];
            ks[j] = mono_key(d) >> 16;
        }
        uint4 w;
        w.x = ks[0] | (ks[1] << 16);
        w.y = ks[2] | (ks[3] << 16);
        w.z = ks[4] | (ks[5] << 16);
        w.w = ks[6] | (ks[7] << 16);
        *(uint4*)&Dk[(size_t)(b*PNUM + p0 + tr + i)*PNUM + q0 + tc] = w;
    }
}

// ---------- bf16 MFMA dist (C=64) ----------
__global__ __launch_bounds__(256) void k_mdist(const float* __restrict__ F,
                                               const float* __restrict__ s,
                                               ushort_t* __restrict__ Dk) {
    __shared__ ushort_t Ap[8][128][8];
    __shared__ ushort_t Aq[8][128][8];
    __shared__ float sp[128], sq[128];
    int b = blockIdx.z;
    int p0 = blockIdx.x*128, q0 = blockIdx.y*128;
    int t = threadIdx.x, lane = t & 63, w = t >> 6;
    int wm = (w >> 1)*64, wn = (w & 1)*64;
    if (t < 128) sp[t] = s[b*PNUM + p0 + t];
    else         sq[t-128] = s[b*PNUM + q0 + (t-128)];
    #pragma unroll
    for (int it = 0; it < 4; it++) {
        int cell = t + 256*it;
        int row = cell >> 3, kg = cell & 7;
        {
            const float* src = &F[(size_t)(b*PNUM + p0 + row)*64 + kg*8];
            float4 fa = *(const float4*)src, fb = *(const float4*)(src + 4);
            uint4 wv;
            wv.x = f2bf(fa.x) | (f2bf(fa.y) << 16);
            wv.y = f2bf(fa.z) | (f2bf(fa.w) << 16);
            wv.z = f2bf(fb.x) | (f2bf(fb.y) << 16);
            wv.w = f2bf(fb.z) | (f2bf(fb.w) << 16);
            *(uint4*)&Ap[kg][row][0] = wv;
        }
        {
            const float* src = &F[(size_t)(b*PNUM + q0 + row)*64 + kg*8];
            float4 fa = *(const float4*)src, fb = *(const float4*)(src + 4);
            uint4 wv;
            wv.x = f2bf(fa.x) | (f2bf(fa.y) << 16);
            wv.y = f2bf(fa.z) | (f2bf(fa.w) << 16);
            wv.z = f2bf(fb.x) | (f2bf(fb.y) << 16);
            wv.w = f2bf(fb.z) | (f2bf(fb.w) << 16);
            *(uint4*)&Aq[kg][row][0] = wv;
        }
    }
    __syncthreads();
    f32x4 acc[4][4] = {};
    #pragma unroll
    for (int ks = 0; ks < 2; ks++) {
        short8v af[4], bf[4];
        #pragma unroll
        for (int mf = 0; mf < 4; mf++)
            af[mf] = *(const short8v*)&Ap[ks*4 + (lane >> 4)][wm + mf*16 + (lane & 15)][0];
        #pragma unroll
        for (int nf = 0; nf < 4; nf++)
            bf[nf] = *(const short8v*)&Aq[ks*4 + (lane >> 4)][wn + nf*16 + (lane & 15)][0];
        #pragma unroll
        for (int mf = 0; mf < 4; mf++)
            #pragma unroll
            for (int nf = 0; nf < 4; nf++)
                acc[mf][nf] = __builtin_amdgcn_mfma_f32_16x16x32_bf16(af[mf], bf[nf], acc[mf][nf], 0, 0, 0);
    }
    int crow = (lane >> 4)*4;
    int ccol = lane & 15;
    #pragma unroll
    for (int mf = 0; mf < 4; mf++) {
        #pragma unroll
        for (int r = 0; r < 4; r++) {
            int row = wm + mf*16 + crow + r;
            float spv = sp[row];
            size_t base = (size_t)(b*PNUM + p0 + row)*PNUM + q0;
            #pragma unroll
            for (int nf = 0; nf < 4; nf++) {
                int col = wn + nf*16 + ccol;
                float d = spv + sq[col] - 2.0f*acc[mf][nf][r];
                Dk[base + col] = (ushort_t)(mono_key(d) >> 16);
            }
        }
    }
}

// ---------- candidate select: binary search threshold on u16 keys; no atomics ----------
__global__ __launch_bounds__(256) void k_topk(const ushort_t* __restrict__ Dk,
                                              int* __restrict__ cand, int* __restrict__ ccnt) {
    __shared__ int red[4];
    __shared__ int wbase[4];
    int n = blockIdx.x, t = threadIdx.x, lane = t & 63, w = t >> 6;
    uint4 wv = *(const uint4*)(Dk + (size_t)n*PNUM + t*8);
    int ks[8];
    ks[0] = wv.x & 0xffff; ks[1] = wv.x >> 16;
    ks[2] = wv.y & 0xffff; ks[3] = wv.y >> 16;
    ks[4] = wv.z & 0xffff; ks[5] = wv.z >> 16;
    ks[6] = wv.w & 0xffff; ks[7] = wv.w >> 16;
    int lo = 0, hi = 65535;
    while (lo < hi) {
        int mid = (lo + hi) >> 1;
        int c = 0;
        #pragma unroll
        for (int e = 0; e < 8; e++) c += (ks[e] <= mid);
        #pragma unroll
        for (int o = 32; o >= 1; o >>= 1) c += __shfl_xor(c, o, 64);
        if (lane == 0) red[w] = c;
        __syncthreads();
        int tot = red[0] + red[1] + red[2] + red[3];
        __syncthreads();
        if (tot >= KSEL) hi = mid; else lo = mid + 1;
    }
    int P = lo;
    int lc = 0;
    #pragma unroll
    for (int e = 0; e < 8; e++) lc += (ks[e] <= P);
    int pre = lc;
    #pragma unroll
    for (int o = 1; o < 64; o <<= 1) { int vv = __shfl_up(pre, o, 64); if (lane >= o) pre += vv; }
    int excl = pre - lc;
    if (lane == 63) red[w] = pre;
    __syncthreads();
    if (t == 0) {
        int s0 = 0;
        #pragma unroll
        for (int i = 0; i < 4; i++) { wbase[i] = s0; s0 += red[i]; }
        ccnt[n] = (s0 < KCAP) ? s0 : KCAP;
    }
    __syncthreads();
    int base = wbase[w] + excl;
    #pragma unroll
    for (int e = 0; e < 8; e++) {
        if (ks[e] <= P) {
            if (base < KCAP) cand[(size_t)n*KCAP + base] = t*8 + e;
            base++;
        }
    }
}

// ---------- refine: f64 distances + all-pairs rank ----------
template<int C>
__global__ __launch_bounds__(256) void k_refine(const float* __restrict__ F,
                                                const int* __restrict__ cand,
                                                const int* __restrict__ ccnt,
                                                int* __restrict__ idx) {
    int t = threadIdx.x;
    int lane = t & 63;
    int row = blockIdx.x*4 + (t >> 6);
    int b = row >> 11;
    const float* fp = F + (size_t)row*C;
    int cnt = ccnt[row];
    bool act = lane < cnt;
    int q = act ? cand[(size_t)row*KCAP + lane] : (lane | 0x40000000);
    const float* fq = F + (size_t)(b*PNUM + (act ? q : 0))*C;
    double d = 1e300;
    if (act) {
        d = 0.0;
        if (C == 64) {
            #pragma unroll
            for (int c4 = 0; c4 < C/4; c4++) {
                float4 a = ((const float4*)fp)[c4];
                float4 bb = ((const float4*)fq)[c4];
                double d0 = (double)a.x - (double)bb.x;
                double d1 = (double)a.y - (double)bb.y;
                double d2 = (double)a.z - (double)bb.z;
                double d3 = (double)a.w - (double)bb.w;
                d += d0*d0 + d1*d1 + d2*d2 + d3*d3;
            }
        } else {
            #pragma unroll
            for (int c = 0; c < C; c++) {
                double df = (double)fp[c] - (double)fq[c];
                d += df*df;
            }
        }
    }
    int rank = 0;
    #pragma unroll 16
    for (int l = 0; l < 64; l++) {
        double dl = lane_bcast64(d, l);
        int ql = __builtin_amdgcn_readlane(q, l);
        rank += (dl < d) || (dl == d && ql < q);
    }
    if (act && rank < KNN) idx[(size_t)row*KNN + rank] = q;
}

// ---------- fused u/v GEMM: u = F@(W0a-W0b)+b0, v = F@W0b ----------
template<int C>
__global__ __launch_bounds__(256) void k_uv(const float* __restrict__ F,
                                            const float* __restrict__ W0,
                                            const float* __restrict__ b0,
                                            float* __restrict__ u, float* __restrict__ v) {
    __shared__ float As[64][17];
    __shared__ float Wa[16][64];
    __shared__ float Wb[16][64];
    int m0 = blockIdx.x*64;
    int t = threadIdx.x;
    int cb = (t & 15)*4, rb = (t >> 4)*4;
    float aU[4][4] = {}, aV[4][4] = {};
    for (int k0 = 0; k0 < C; k0 += 16) {
        #pragma unroll
        for (int j = 0; j < 4; j++) {
            int e = t + 256*j;
            int r = e >> 4, c = e & 15;
            As[r][c] = (k0 + c < C) ? F[(size_t)(m0 + r)*C + k0 + c] : 0.f;
        }
        {
            int r = t >> 4, c4 = (t & 15)*4;
            bool ok = (k0 + r < C);
            float4 wa = ok ? *(const float4*)&W0[(size_t)(k0 + r)*64 + c4] : make_float4(0,0,0,0);
            float4 wb = ok ? *(const float4*)&W0[(size_t)(C + k0 + r)*64 + c4] : make_float4(0,0,0,0);
            *(float4*)&Wa[r][c4] = wa;
            *(float4*)&Wb[r][c4] = wb;
        }
        __syncthreads();
        #pragma unroll
        for (int kk = 0; kk < 16; kk++) {
            float a[4];
            #pragma unroll
            for (int i = 0; i < 4; i++) a[i] = As[rb + i][kk];
            float4 wa4 = *(const float4*)&Wa[kk][cb];
            float4 wb4 = *(const float4*)&Wb[kk][cb];
            float wa[4] = {wa4.x, wa4.y, wa4.z, wa4.w};
            float wb[4] = {wb4.x, wb4.y, wb4.z, wb4.w};
            #pragma unroll
            for (int i = 0; i < 4; i++)
                #pragma unroll
                for (int j = 0; j < 4; j++) {
                    aU[i][j] = fmaf(a[i], wa[j] - wb[j], aU[i][j]);
                    aV[i][j] = fmaf(a[i], wb[j], aV[i][j]);
                }
        }
        __syncthreads();
    }
    #pragma unroll
    for (int i = 0; i < 4; i++) {
        int row = m0 + rb + i;
        #pragma unroll
        for (int j = 0; j < 4; j++) {
            int col = cb + j;
            u[(size_t)row*64 + col] = aU[i][j] + b0[col];
            v[(size_t)row*64 + col] = aV[i][j];
        }
    }
}

// ---------- 64-wide tiled f32 GEMM (final ho layer) ----------
template<int RELU>
__global__ __launch_bounds__(256) void k_gemm(const float* __restrict__ A,
                                              const float* __restrict__ W,
                                              const float* __restrict__ bias,
                                              float* __restrict__ out,
                                              int M, int Kd, int Nd) {
    __shared__ float As[64][17];
    __shared__ float Bs[16][64];
    int m0 = blockIdx.x*64, n0 = blockIdx.y*64;
    int t = threadIdx.x;
    int cb = (t & 15)*4, rb = (t >> 4)*4;
    float acc[4][4] = {};
    for (int k0 = 0; k0 < Kd; k0 += 16) {
        #pragma unroll
        for (int j = 0; j < 4; j++) {
            int e = t + 256*j;
            int r = e >> 4, c = e & 15;
            As[r][c] = (k0 + c < Kd) ? A[(size_t)(m0 + r)*Kd + k0 + c] : 0.f;
        }
        #pragma unroll
        for (int j = 0; j < 4; j++) {
            int e = t + 256*j;
            int r = e >> 6, c = e & 63;
            Bs[r][c] = (k0 + r < Kd && n0 + c < Nd) ? W[(size_t)(k0 + r)*Nd + n0 + c] : 0.f;
        }
        __syncthreads();
        #pragma unroll
        for (int kk = 0; kk < 16; kk++) {
            float a[4];
            #pragma unroll
            for (int i = 0; i < 4; i++) a[i] = As[rb + i][kk];
            float4 w4 = *(const float4*)&Bs[kk][cb];
            float w[4] = {w4.x, w4.y, w4.z, w4.w};
            #pragma unroll
            for (int i = 0; i < 4; i++)
                #pragma unroll
                for (int j = 0; j < 4; j++) acc[i][j] += a[i]*w[j];
        }
        __syncthreads();
    }
    #pragma unroll
    for (int i = 0; i < 4; i++) {
        int row = m0 + rb + i;
        #pragma unroll
        for (int j = 0; j < 4; j++) {
            int col = n0 + cb + j;
            if (col < Nd) {
                float v = acc[i][j] + (bias ? bias[col] : 0.f);
                if (RELU) v = fmaxf(v, 0.f);
                out[(size_t)row*Nd + col] = v;
            }
        }
    }
}

// ---------- pack f32 weights [Kd][Nd] -> bf16 fragment layout [(Kd/8)][Nd][8] ----------
__global__ void k_pack(const float* __restrict__ W, ushort_t* __restrict__ Wpk,
                       int Kd, int Nd) {
    int cell = blockIdx.x*256 + threadIdx.x;
    int ncell = (Kd >> 3)*Nd;
    if (cell >= ncell) return;
    int kg = cell / Nd, n = cell - kg*Nd;
    unsigned b[8];
    #pragma unroll
    for (int j = 0; j < 8; j++) b[j] = f2bf(W[(size_t)(kg*8 + j)*Nd + n]);
    uint4 wv;
    wv.x = b[0] | (b[1] << 16); wv.y = b[2] | (b[3] << 16);
    wv.z = b[4] | (b[5] << 16); wv.w = b[6] | (b[7] << 16);
    *(uint4*)&Wpk[(size_t)cell*8] = wv;
}

// ---------- bf16 MFMA GEMM: 128x128 tile, 4 waves (2x2 of 64x64), f32 out ----------
template<int CONCAT, int RELU>
__global__ __launch_bounds__(256) void k_mgemm(const float* __restrict__ A,
                                               const float* __restrict__ A2,
                                               const float* __restrict__ A3,
                                               const ushort_t* __restrict__ Wpk,
                                               const float* __restrict__ bias,
                                               float* __restrict__ out,
                                               int Kd, int Nd) {
    __shared__ ushort_t Al[4][128][8];
    __shared__ ushort_t Bl[4][128][8];
    int m0 = blockIdx.x*128, n0 = blockIdx.y*128;
    int t = threadIdx.x, lane = t & 63, w = t >> 6;
    int wm = (w >> 1)*64, wn = (w & 1)*64;
    f32x4 acc[4][4] = {};
    int arow = t >> 2, akg = t & 3;
    for (int k0 = 0; k0 < Kd; k0 += 32) {
        #pragma unroll
        for (int i = 0; i < 2; i++) {
            int row = arow + 64*i;
            int kb = k0 + akg*8;
            const float* src;
            if (CONCAT) {
                const float* s0 = (kb < 64) ? A : (kb < 128) ? A2 : A3;
                src = s0 + (size_t)(m0 + row)*64 + (kb & 63);
            } else {
                src = A + (size_t)(m0 + row)*Kd + kb;
            }
            float4 fa = *(const float4*)src;
            float4 fb = *(const float4*)(src + 4);
            uint4 wv;
            wv.x = f2bf(fa.x) | (f2bf(fa.y) << 16);
            wv.y = f2bf(fa.z) | (f2bf(fa.w) << 16);
            wv.z = f2bf(fb.x) | (f2bf(fb.y) << 16);
            wv.w = f2bf(fb.z) | (f2bf(fb.w) << 16);
            *(uint4*)&Al[akg][row][0] = wv;
        }
        #pragma unroll
        for (int i = 0; i < 2; i++) {
            int cell = t + 256*i;
            int kg = cell >> 7, col = cell & 127;
            *(uint4*)&Bl[kg][col][0] =
                *(const uint4*)&Wpk[((size_t)(k0/8 + kg)*Nd + n0 + col)*8];
        }
        __syncthreads();
        short8v af[4], bf[4];
        #pragma unroll
        for (int mf = 0; mf < 4; mf++)
            af[mf] = *(const short8v*)&Al[lane >> 4][wm + mf*16 + (lane & 15)][0];
        #pragma unroll
        for (int nf = 0; nf < 4; nf++)
            bf[nf] = *(const short8v*)&Bl[lane >> 4][wn + nf*16 + (lane & 15)][0];
        #pragma unroll
        for (int mf = 0; mf < 4; mf++)
            #pragma unroll
            for (int nf = 0; nf < 4; nf++)
                acc[mf][nf] = __builtin_amdgcn_mfma_f32_16x16x32_bf16(af[mf], bf[nf], acc[mf][nf], 0, 0, 0);
        __syncthreads();
    }
    int crow = (lane >> 4)*4;
    int ccol = lane & 15;
    #pragma unroll
    for (int nf = 0; nf < 4; nf++) {
        int col = n0 + wn + nf*16 + ccol;
        float bv = bias[col];
        #pragma unroll
        for (int mf = 0; mf < 4; mf++) {
            #pragma unroll
            for (int r = 0; r < 4; r++) {
                int row = m0 + wm + mf*16 + crow + r;
                float vv = acc[mf][nf][r] + bv;
                if (RELU) vv = fmaxf(vv, 0.f);
                out[(size_t)row*Nd + col] = vv;
            }
        }
    }
}

// ---------- stats of relu(u_p + v_q) over all edges (float4 vectorized) ----------
__global__ __launch_bounds__(256) void k_e1stats(const float* __restrict__ u,
                                                 const float* __restrict__ v,
                                                 const int* __restrict__ idx,
                                                 float* __restrict__ psum, float* __restrict__ psq) {
    int t = threadIdx.x;
    float s0 = 0.f, s1 = 0.f, s2 = 0.f, s3 = 0.f;
    float q0 = 0.f, q1 = 0.f, q2 = 0.f, q3 = 0.f;
    const int stride = 3840*256;
    int i = blockIdx.x*256 + t;
    int c4 = (i & 15)*4;
    #pragma unroll 1
    for (int j = 0; j < 8; j++, i += stride) {
        int edge = i >> 4;
        int p = edge / KNN;
        int q = idx[edge];
        int b = p >> 11;
        float4 uv = *(const float4*)&u[(size_t)p*64 + c4];
        float4 vv = *(const float4*)&v[(size_t)(b*PNUM + q)*64 + c4];
        float h0 = fmaxf(uv.x + vv.x, 0.f);
        float h1 = fmaxf(uv.y + vv.y, 0.f);
        float h2 = fmaxf(uv.z + vv.z, 0.f);
        float h3 = fmaxf(uv.w + vv.w, 0.f);
        s0 += h0; s1 += h1; s2 += h2; s3 += h3;
        q0 = fmaf(h0, h0, q0); q1 = fmaf(h1, h1, q1);
        q2 = fmaf(h2, h2, q2); q3 = fmaf(h3, h3, q3);
    }
    __shared__ float rs[16][16][4];
    __shared__ float rq[16][16][4];
    int slot = t >> 4, g = t & 15;
    rs[slot][g][0] = s0; rs[slot][g][1] = s1; rs[slot][g][2] = s2; rs[slot][g][3] = s3;
    rq[slot][g][0] = q0; rq[slot][g][1] = q1; rq[slot][g][2] = q2; rq[slot][g][3] = q3;
    __syncthreads();
    if (t < 64) {
        int gg = t >> 2, comp = t & 3;
        float ss = 0.f, qq = 0.f;
        #pragma unroll
        for (int sl = 0; sl < 16; sl++) { ss += rs[sl][gg][comp]; qq += rq[sl][gg][comp]; }
        psum[(size_t)blockIdx.x*64 + t] = ss;
        psq [(size_t)blockIdx.x*64 + t] = qq;
    }
}

// ---------- finalize BN stats ----------
__global__ void k_statsfin(const float* __restrict__ psum, const float* __restrict__ psq,
                           int npart, int C, float invM,
                           const float* __restrict__ g, const float* __restrict__ be,
                           float* __restrict__ scale, float* __restrict__ shift) {
    int c = blockIdx.x, t = threadIdx.x;
    float s = 0.f, q = 0.f;
    for (int i = t; i < npart; i += 256) {
        s += psum[(size_t)i*C + c];
        q += psq [(size_t)i*C + c];
    }
    __shared__ float rs[256], rq[256];
    rs[t] = s; rq[t] = q; __syncthreads();
    for (int off = 128; off >= 1; off >>= 1) {
        if (t < off) { rs[t] += rs[t+off]; rq[t] += rq[t+off]; }
        __syncthreads();
    }
    if (t == 0) {
        float m   = rs[0]*invM;
        float var = rq[0]*invM - m*m;
        float inv = rsqrtf(var + EPSF);
        float sc  = g[c]*inv;
        scale[c] = sc;
        shift[c] = be[c] - m*sc;
    }
}

// ---------- fold BN affine into next linear (head layers) ----------
__global__ void k_fold(const float* __restrict__ W, const float* __restrict__ b,
                       const float* __restrict__ scale, const float* __restrict__ shift,
                       float* __restrict__ Wp, float* __restrict__ bp, int Cin, int Cout) {
    int co = blockIdx.x, t = threadIdx.x;
    float acc = 0.f;
    for (int ci = t; ci < Cin; ci += 256) {
        float w = W[(size_t)ci*Cout + co];
        Wp[(size_t)ci*Cout + co] = scale[ci]*w;
        acc += shift[ci]*w;
    }
    __shared__ float r[256];
    r[t] = acc; __syncthreads();
    for (int off = 128; off >= 1; off >>= 1) { if (t < off) r[t] += r[t+off]; __syncthreads(); }
    if (t == 0) bp[co] = b[co] + r[0];
}

// ---------- conv fold: identical bp math to k_fold, plus row-major Wp AND transposed W1t ----------
__global__ void k_fold64T(const float* __restrict__ W, const float* __restrict__ b,
                          const float* __restrict__ scale, const float* __restrict__ shift,
                          float* __restrict__ Wp, float* __restrict__ W1t, float* __restrict__ bp) {
    int co = blockIdx.x, t = threadIdx.x;   // 64 blocks x 256 threads (t>=64 idle in loop)
    float acc = 0.f;
    for (int ci = t; ci < 64; ci += 256) {
        float w = W[(size_t)ci*64 + co];
        float sw = scale[ci]*w;
        Wp [(size_t)ci*64 + co] = sw;       // row-major (conv3 pack path)
        W1t[(size_t)co*64 + ci] = sw;       // transposed (f32 e2 path)
        acc += shift[ci]*w;
    }
    __shared__ float r[256];
    r[t] = acc; __syncthreads();
    for (int off = 128; off >= 1; off >>= 1) { if (t < off) r[t] += r[t+off]; __syncthreads(); }
    if (t == 0) bp[co] = b[co] + r[0];
}

// ---------- edge layer 1 (f32, kNN-feeding convs): transposed weights -> f32x4 loads ----------
__global__ __launch_bounds__(256, 4) void k_e2(const float* __restrict__ u, const float* __restrict__ v,
                                               const int* __restrict__ idx,
                                               const float* __restrict__ W1t, const float* __restrict__ b1p,
                                               float* __restrict__ pmax, float* __restrict__ pmin,
                                               float* __restrict__ psum, float* __restrict__ psq) {
    __shared__ float hbuf[4][64];
    int t = threadIdx.x, lane = t & 63, w = t >> 6;
    int p = blockIdx.x*4 + w;
    int b = p >> 11;
    // lane's weight column = contiguous 256B row of W1t -> 16 x f32x4 (same values,
    // same FMA pairing as before => bit-identical output; only the layout changed)
    f32x4 wc[16];
    #pragma unroll
    for (int i = 0; i < 16; i++) wc[i] = *(const f32x4*)&W1t[(size_t)lane*64 + i*4];
    float ureg = u[(size_t)p*64 + lane];
    float bias = b1p[lane];
    const int* myidx = idx + (size_t)p*KNN;
    const float* vb = v + (size_t)b*PNUM*64;
    float mx = -1e30f, mn = 1e30f, sm = 0.f, sq = 0.f;
    int q = myidx[0];
    float vk = vb[(size_t)q*64 + lane];
    #pragma unroll 1
    for (int k = 0; k < KNN; k++) {
        float h = fmaxf(ureg + vk, 0.f);
        hbuf[w][lane] = h;
        if (k + 1 < KNN) {
            int qn = myidx[k + 1];
            vk = vb[(size_t)qn*64 + lane];
        }
        float a0 = 0.f, a1 = 0.f, a2 = 0.f, a3 = 0.f;
        #pragma unroll
        for (int i = 0; i < 16; i++) {
            float4 h4 = *(const float4*)&hbuf[w][i*4];
            a0 = fmaf(h4.x, wc[i][0], a0);
            a1 = fmaf(h4.y, wc[i][1], a1);
            a2 = fmaf(h4.z, wc[i][2], a2);
            a3 = fmaf(h4.w, wc[i][3], a3);
        }
        float o = fmaxf((a0 + a1) + (a2 + a3) + bias, 0.f);
        mx = fmaxf(mx, o);
        mn = fminf(mn, o);
        sm += o;
        sq = fmaf(o, o, sq);
    }
    pmax[(size_t)p*64 + lane] = mx;
    pmin[(size_t)p*64 + lane] = mn;
    psum[(size_t)p*64 + lane] = sm;
    psq [(size_t)p*64 + lane] = sq;
}

// ---------- edge layer 1 (bf16 MFMA, conv3 only — x3 feeds no kNN) ----------
__global__ __launch_bounds__(256) void k_e2m(const float* __restrict__ u, const float* __restrict__ v,
                                             const int* __restrict__ idx,
                                             const ushort_t* __restrict__ Wpk, const float* __restrict__ b1p,
                                             float* __restrict__ pmax, float* __restrict__ pmin,
                                             float* __restrict__ psum, float* __restrict__ psq) {
    __shared__ int idxs[4][32];
    int t = threadIdx.x, lane = t & 63, w = t >> 6;
    int p = blockIdx.x*4 + w;
    int b = p >> 11;
    if (lane < 32) idxs[w][lane] = (lane < KNN) ? idx[(size_t)p*KNN + lane] : -1;
    const float* vb = v + (size_t)b*PNUM*64;
    int oct = lane >> 4;
    int col16 = lane & 15;
    float uo[2][8];
    #pragma unroll
    for (int kb = 0; kb < 2; kb++) {
        const float* up = &u[(size_t)p*64 + kb*32 + oct*8];
        float4 a = *(const float4*)up;
        float4 bq = *(const float4*)(up + 4);
        uo[kb][0]=a.x; uo[kb][1]=a.y; uo[kb][2]=a.z; uo[kb][3]=a.w;
        uo[kb][4]=bq.x; uo[kb][5]=bq.y; uo[kb][6]=bq.z; uo[kb][7]=bq.w;
    }
    short8v af[2][2];
    #pragma unroll
    for (int mf = 0; mf < 2; mf++) {
        int r = mf*16 + col16;
        int q = idxs[w][r];
        #pragma unroll
        for (int kb = 0; kb < 2; kb++) {
            uint4 wv = make_uint4(0u, 0u, 0u, 0u);
            if (q >= 0) {
                const float* vp = &vb[(size_t)q*64 + kb*32 + oct*8];
                float4 va = *(const float4*)vp;
                float4 vbq = *(const float4*)(vp + 4);
                float h0 = fmaxf(uo[kb][0] + va.x,  0.f);
                float h1 = fmaxf(uo[kb][1] + va.y,  0.f);
                float h2 = fmaxf(uo[kb][2] + va.z,  0.f);
                float h3 = fmaxf(uo[kb][3] + va.w,  0.f);
                float h4 = fmaxf(uo[kb][4] + vbq.x, 0.f);
                float h5 = fmaxf(uo[kb][5] + vbq.y, 0.f);
                float h6 = fmaxf(uo[kb][6] + vbq.z, 0.f);
                float h7 = fmaxf(uo[kb][7] + vbq.w, 0.f);
                wv.x = f2bf(h0) | (f2bf(h1) << 16);
                wv.y = f2bf(h2) | (f2bf(h3) << 16);
                wv.z = f2bf(h4) | (f2bf(h5) << 16);
                wv.w = f2bf(h6) | (f2bf(h7) << 16);
            }
            union { uint4 ui; short8v sv; } cvt; cvt.ui = wv;
            af[mf][kb] = cvt.sv;
        }
    }
    short8v bf[2][4];
    #pragma unroll
    for (int kb = 0; kb < 2; kb++)
        #pragma unroll
        for (int nf = 0; nf < 4; nf++)
            bf[kb][nf] = *(const short8v*)&Wpk[((size_t)(kb*4 + oct)*64 + nf*16 + col16)*8];
    f32x4 acc[2][4] = {};
    #pragma unroll
    for (int kb = 0; kb < 2; kb++)
        #pragma unroll
        for (int mf = 0; mf < 2; mf++)
            #pragma unroll
            for (int nf = 0; nf < 4; nf++)
                acc[mf][nf] = __builtin_amdgcn_mfma_f32_16x16x32_bf16(af[mf][kb], bf[kb][nf], acc[mf][nf], 0, 0, 0);
    #pragma unroll
    for (int nf = 0; nf < 4; nf++) {
        float bj = b1p[nf*16 + col16];
        float mx = -1e30f, mn = 1e30f, sm = 0.f, sq = 0.f;
        #pragma unroll
        for (int mf = 0; mf < 2; mf++)
            #pragma unroll
            for (int r4 = 0; r4 < 4; r4++) {
                int row = mf*16 + oct*4 + r4;
                if (row < KNN) {
                    float o = fmaxf(acc[mf][nf][r4] + bj, 0.f);
                    mx = fmaxf(mx, o);
                    mn = fminf(mn, o);
                    sm += o;
                    sq = fmaf(o, o, sq);
                }
            }
        mx = fmaxf(mx, __shfl_xor(mx, 16, 64));
        mn = fminf(mn, __shfl_xor(mn, 16, 64));
        sm += __shfl_xor(sm, 16, 64);
        sq += __shfl_xor(sq, 16, 64);
        mx = fmaxf(mx, __shfl_xor(mx, 32, 64));
        mn = fminf(mn, __shfl_xor(mn, 32, 64));
        sm += __shfl_xor(sm, 32, 64);
        sq += __shfl_xor(sq, 32, 64);
        if (oct == 0) {
            int col = nf*16 + col16;
            pmax[(size_t)p*64 + col] = mx;
            pmin[(size_t)p*64 + col] = mn;
            psum[(size_t)p*64 + col] = sm;
            psq [(size_t)p*64 + col] = sq;
        }
    }
}

// ---------- BN1 applied after pooling (max if scale>=0 else min) ----------
__global__ void k_applypool(const float* __restrict__ pmax, const float* __restrict__ pmin,
                            const float* __restrict__ scale, const float* __restrict__ shift,
                            float* __restrict__ out) {
    int i = blockIdx.x*256 + threadIdx.x;
    int c = i & 63;
    float sc = scale[c];
    float pooled = (sc >= 0.f) ? pmax[i] : pmin[i];
    out[i] = sc*pooled + shift[c];
}

// ---------- per-column partial sums over 64-row blocks ----------
__global__ void k_colstats(const float* __restrict__ Hbuf, float* __restrict__ psum,
                           float* __restrict__ psq, int Cout) {
    int m0 = blockIdx.x*64, c0 = blockIdx.y*64;
    int t = threadIdx.x;
    int c = t & 63, rg = t >> 6;
    float s = 0.f, q = 0.f;
    #pragma unroll 4
    for (int r = 0; r < 16; r++) {
        float hv = Hbuf[(size_t)(m0 + rg*16 + r)*Cout + c0 + c];
        s += hv; q += hv*hv;
    }
    __shared__ float rs[256], rq[256];
    rs[t] = s; rq[t] = q; __syncthreads();
    if (t < 128) { rs[t] += rs[t+128]; rq[t] += rq[t+128]; }
    __syncthreads();
    if (t < 64) {
        rs[t] += rs[t+64]; rq[t] += rq[t+64];
        psum[(size_t)blockIdx.x*Cout + c0 + t] = rs[t];
        psq [(size_t)blockIdx.x*Cout + c0 + t] = rq[t];
    }
}

// ---------- log_softmax over 50 cols, one wave per row ----------
__global__ void k_logsoftmax(const float* __restrict__ logits, float* __restrict__ out) {
    int t = threadIdx.x;
    int n = blockIdx.x*4 + (t >> 6);
    int l = t & 63;
    float z = (l < 50) ? logits[(size_t)n*50 + l] : -INFINITY;
    float mx = z;
    #pragma unroll
    for (int off = 32; off >= 1; off >>= 1) mx = fmaxf(mx, __shfl_xor(mx, off, 64));
    float ex = (l < 50) ? expf(z - mx) : 0.f;
    float sm = ex;
    #pragma unroll
    for (int off = 32; off >= 1; off >>= 1) sm += __shfl_xor(sm, off, 64);
    float lse = mx + logf(sm);
    if (l < 50) out[(size_t)n*50 + l] = z - lse;
}

extern "C" void kernel_launch(void* const* d_in, const int* in_sizes, int n_in,
                              void* d_out, int out_size, void* d_ws, size_t ws_size,
                              hipStream_t stream) {
    (void)in_sizes; (void)n_in; (void)out_size;
    const float* x   = (const float*)d_in[0];
    const float* pos = (const float*)d_in[1];
    const float* prm[38];
    for (int i = 0; i < 38; i++) prm[i] = (const float*)d_in[3 + i];
    // prm: c1[0..7] c2[8..15] c3[16..23] l1[24..27] h0[28..31] h1[32..35] ho[36..37]

    float* ws = (float*)d_ws;
    size_t off = 0;
    auto alloc = [&](size_t cnt) { float* p = ws + off; off += (cnt + 63) & ~((size_t)63); return p; };
    float* f0   = alloc((size_t)NPT*6);
    float* s    = alloc(NPT);
    float* x1   = alloc((size_t)NPT*64);
    float* x2   = alloc((size_t)NPT*64);
    float* x3   = alloc((size_t)NPT*64);
    float* u    = alloc((size_t)NPT*64);
    float* v    = alloc((size_t)NPT*64);
    float* pmax = alloc((size_t)NPT*64);
    float* pmin = alloc((size_t)NPT*64);
    int*   idx  = (int*)alloc((size_t)NPT*KNN);
    int*   ccnt = (int*)alloc(NPT);
    float* W1p  = alloc(64*64);
    float* W1t  = alloc(64*64);
    float* b1p  = alloc(64);
    float* scaleA = alloc(1024);
    float* shiftA = alloc(1024);
    float* Wp   = alloc(1024*256);
    float* bp   = alloc(1024);
    ushort_t* Wpk1 = (ushort_t*)alloc(98304);    // l1 packed weights (192*1024 bf16)
    ushort_t* Wpk2 = (ushort_t*)alloc(131072);   // h0/h1 + conv3-e2 packed weights
    float* psum = alloc((size_t)NPT*64);
    float* psq  = alloc((size_t)NPT*64);
    float* big  = alloc((size_t)BNUM*PNUM*PNUM);   // shared: Dk (u16), then head activations
    if (off*sizeof(float) > ws_size) return;       // insufficient workspace -> leave poisoned

    int* cand = (int*)psum;
    ushort_t* Dk = (ushort_t*)big;

    auto conv = [&](const float* F, int C, const float* const* pp, float* xout, bool mfma_e2) {
        if (C == 6) {
            k_dist<6><<<dim3(16,16,8), 256, 0, stream>>>(F, Dk);
        } else {
            k_snorm<64><<<NPT/256, 256, 0, stream>>>(F, s);
            k_mdist<<<dim3(16,16,8), 256, 0, stream>>>(F, s, Dk);
        }
        k_topk<<<NPT, 256, 0, stream>>>(Dk, cand, ccnt);
        if (C == 6) k_refine<6><<<NPT/4, 256, 0, stream>>>(F, cand, ccnt, idx);
        else        k_refine<64><<<NPT/4, 256, 0, stream>>>(F, cand, ccnt, idx);
        if (C == 6) k_uv<6><<<NPT/64, 256, 0, stream>>>(F, pp[0], pp[1], u, v);
        else        k_uv<64><<<NPT/64, 256, 0, stream>>>(F, pp[0], pp[1], u, v);
        k_e1stats<<<3840, 256, 0, stream>>>(u, v, idx, psum, psq);
        k_statsfin<<<64, 256, 0, stream>>>(psum, psq, 3840, 64, 1.f/((float)NPT*KNN),
                                           pp[2], pp[3], scaleA, shiftA);
        k_fold64T<<<64, 256, 0, stream>>>(pp[4], pp[5], scaleA, shiftA, W1p, W1t, b1p);
        if (mfma_e2) {
            k_pack<<<2, 256, 0, stream>>>(W1p, Wpk2, 64, 64);
            k_e2m<<<NPT/4, 256, 0, stream>>>(u, v, idx, Wpk2, b1p, pmax, pmin, psum, psq);
        } else {
            k_e2<<<NPT/4, 256, 0, stream>>>(u, v, idx, W1t, b1p, pmax, pmin, psum, psq);
        }
        k_statsfin<<<64, 256, 0, stream>>>(psum, psq, NPT, 64, 1.f/((float)NPT*KNN),
                                           pp[6], pp[7], scaleA, shiftA);
        k_applypool<<<NPT*64/256, 256, 0, stream>>>(pmax, pmin, scaleA, shiftA, xout);
    };

    k_concat6<<<NPT*6/256, 256, 0, stream>>>(x, pos, f0);
    k_pack<<<96, 256, 0, stream>>>(prm[24], Wpk1, 192, 1024);   // l1 weights
    conv(f0, 6,  &prm[0],  x1, false);   // x1 feeds kNN2 -> f32 e2
    conv(x1, 64, &prm[8],  x2, false);   // x2 feeds kNN3 -> f32 e2
    conv(x2, 64, &prm[16], x3, true);    // x3 head-only -> bf16 MFMA e2

    float* Hb1    = big + 3145728;
    float* Hb2    = big + 19922944;
    float* Hb3    = big + 24117248;
    float* logits = big + 26214400;

    k_mgemm<1,1><<<dim3(NPT/128, 8), 256, 0, stream>>>(x1, x2, x3, Wpk1, prm[25], Hb1, 192, 1024);
    k_colstats<<<dim3(NPT/64, 16), 256, 0, stream>>>(Hb1, psum, psq, 1024);
    k_statsfin<<<1024, 256, 0, stream>>>(psum, psq, NPT/64, 1024, 1.f/(float)NPT,
                                         prm[26], prm[27], scaleA, shiftA);
    k_fold<<<256, 256, 0, stream>>>(prm[28], prm[29], scaleA, shiftA, Wp, bp, 1024, 256);
    k_pack<<<128, 256, 0, stream>>>(Wp, Wpk2, 1024, 256);
    k_mgemm<0,1><<<dim3(NPT/128, 2), 256, 0, stream>>>(Hb1, nullptr, nullptr, Wpk2, bp, Hb2, 1024, 256);
    k_colstats<<<dim3(NPT/64, 4), 256, 0, stream>>>(Hb2, psum, psq, 256);
    k_statsfin<<<256, 256, 0, stream>>>(psum, psq, NPT/64, 256, 1.f/(float)NPT,
                                        prm[30], prm[31], scaleA, shiftA);
    k_fold<<<128, 256, 0, stream>>>(prm[32], prm[33], scaleA, shiftA, Wp, bp, 256, 128);
    k_pack<<<16, 256, 0, stream>>>(Wp, Wpk2, 256, 128);
    k_mgemm<0,1><<<dim3(NPT/128, 1), 256, 0, stream>>>(Hb2, nullptr, nullptr, Wpk2, bp, Hb3, 256, 128);
    k_colstats<<<dim3(NPT/64, 2), 256, 0, stream>>>(Hb3, psum, psq, 128);
    k_statsfin<<<128, 256, 0, stream>>>(psum, psq, NPT/64, 128, 1.f/(float)NPT,
                                        prm[34], prm[35], scaleA, shiftA);
    k_fold<<<50, 256, 0, stream>>>(prm[36], prm[37], scaleA, shiftA, Wp, bp, 128, 50);
    k_gemm<0><<<dim3(NPT/64, 1), 256, 0, stream>>>(Hb3, Wp, bp, logits, NPT, 128, 50);
    k_logsoftmax<<<NPT/4, 256, 0, stream>>>(logits, (float*)d_out);
}

// Round 17
// 1013.967 us; speedup vs baseline: 1.0502x; 1.0502x over previous
//
#include <hip/hip_runtime.h>
#include <hip/hip_bf16.h>
#include <stdint.h>

#define BNUM 8
#define PNUM 2048
#define KNN  30
#define KSEL 40      // rank threshold for candidate selection
#define KCAP 64      // max candidates per row (one wave in refine)
#define NPT  (BNUM*PNUM)   // 16384
#define EPSF 1e-5f

typedef unsigned long long u64;
typedef unsigned short ushort_t;
typedef __attribute__((ext_vector_type(8))) short short8v;   // 8 bf16 (4 VGPRs)
typedef __attribute__((ext_vector_type(4))) float f32x4;

__device__ __forceinline__ unsigned mono_key(float d) {
    unsigned u = __float_as_uint(d);
    return (u & 0x80000000u) ? ~u : (u | 0x80000000u);   // monotone float->uint
}

__device__ __forceinline__ unsigned f2bf(float f) {      // f32 -> bf16 bits, RNE
    unsigned u = __float_as_uint(f);
    u += 0x7fffu + ((u >> 16) & 1u);
    return u >> 16;
}

__device__ __forceinline__ double lane_bcast64(double x, int l) {   // uniform l -> v_readlane
    union { double d; int i[2]; } a; a.d = x;
    union { int i[2]; double d; } r;
    r.i[0] = __builtin_amdgcn_readlane(a.i[0], l);
    r.i[1] = __builtin_amdgcn_readlane(a.i[1], l);
    return r.d;
}

// ---------- f0 = concat(x, pos) ----------
__global__ void k_concat6(const float* __restrict__ x, const float* __restrict__ pos,
                          float* __restrict__ f0) {
    int i = blockIdx.x*256 + threadIdx.x;        // < N*6
    int n = i/6, c = i%6;
    f0[i] = (c < 3) ? x[n*3 + c] : pos[n*3 + c - 3];
}

// ---------- s[n] = sum_c F[n][c]^2 ----------
template<int C>
__global__ void k_snorm(const float* __restrict__ F, float* __restrict__ s) {
    int n = blockIdx.x*256 + threadIdx.x;
    float a = 0.f;
    for (int c = 0; c < C; c++) { float t = F[(size_t)n*C + c]; a = fmaf(t, t, a); }
    s[n] = a;
}

// ---------- f32 dist (C=6 only): 128x128 tile, snorm fused ----------
template<int C>
__global__ __launch_bounds__(256) void k_dist(const float* __restrict__ F,
                                              ushort_t* __restrict__ Dk) {
    __shared__ float FpT[C][132];
    __shared__ float FqT[C][132];
    __shared__ float sp[128], sq[128];
    int b = blockIdx.z;
    int p0 = blockIdx.x*128, q0 = blockIdx.y*128;
    int t = threadIdx.x;
    for (int e = t; e < 128*C; e += 256) {
        int r = e / C, c = e % C;
        FpT[c][r] = F[(size_t)(b*PNUM + p0 + r)*C + c];
        FqT[c][r] = F[(size_t)(b*PNUM + q0 + r)*C + c];
    }
    __syncthreads();
    if (t < 128) {
        float a = 0.f;
        for (int c = 0; c < C; c++) { float xv = FpT[c][t]; a = fmaf(xv, xv, a); }
        sp[t] = a;
    } else {
        int r = t - 128;
        float a = 0.f;
        for (int c = 0; c < C; c++) { float xv = FqT[c][r]; a = fmaf(xv, xv, a); }
        sq[r] = a;
    }
    __syncthreads();
    int tc = (t & 15)*8, tr = (t >> 4)*8;
    float acc[8][8] = {};
    for (int c = 0; c < C; c++) {
        float4 p0v = *(const float4*)&FpT[c][tr];
        float4 p1v = *(const float4*)&FpT[c][tr+4];
        float4 q0v = *(const float4*)&FqT[c][tc];
        float4 q1v = *(const float4*)&FqT[c][tc+4];
        float av[8] = {p0v.x,p0v.y,p0v.z,p0v.w,p1v.x,p1v.y,p1v.z,p1v.w};
        float bv[8] = {q0v.x,q0v.y,q0v.z,q0v.w,q1v.x,q1v.y,q1v.z,q1v.w};
        #pragma unroll
        for (int i = 0; i < 8; i++)
            #pragma unroll
            for (int j = 0; j < 8; j++) acc[i][j] = fmaf(av[i], bv[j], acc[i][j]);
    }
    #pragma unroll
    for (int i = 0; i < 8; i++) {
        unsigned ks[8];
        #pragma unroll
        for (int j = 0; j < 8; j++) {
            float d = sp[tr + i] + sq[tc + j] - 2.0f*acc[i][j];
            ks[j] = mono_key(d) >> 16;
        }
        uint4 w;
        w.x = ks[0] | (ks[1] << 16);
        w.y = ks[2] | (ks[3] << 16);
        w.z = ks[4] | (ks[5] << 16);
        w.w = ks[6] | (ks[7] << 16);
        *(uint4*)&Dk[(size_t)(b*PNUM + p0 + tr + i)*PNUM + q0 + tc] = w;
    }
}

// ---------- bf16 MFMA dist (C=64) ----------
__global__ __launch_bounds__(256) void k_mdist(const float* __restrict__ F,
                                               const float* __restrict__ s,
                                               ushort_t* __restrict__ Dk) {
    __shared__ ushort_t Ap[8][128][8];
    __shared__ ushort_t Aq[8][128][8];
    __shared__ float sp[128], sq[128];
    int b = blockIdx.z;
    int p0 = blockIdx.x*128, q0 = blockIdx.y*128;
    int t = threadIdx.x, lane = t & 63, w = t >> 6;
    int wm = (w >> 1)*64, wn = (w & 1)*64;
    if (t < 128) sp[t] = s[b*PNUM + p0 + t];
    else         sq[t-128] = s[b*PNUM + q0 + (t-128)];
    #pragma unroll
    for (int it = 0; it < 4; it++) {
        int cell = t + 256*it;
        int row = cell >> 3, kg = cell & 7;
        {
            const float* src = &F[(size_t)(b*PNUM + p0 + row)*64 + kg*8];
            float4 fa = *(const float4*)src, fb = *(const float4*)(src + 4);
            uint4 wv;
            wv.x = f2bf(fa.x) | (f2bf(fa.y) << 16);
            wv.y = f2bf(fa.z) | (f2bf(fa.w) << 16);
            wv.z = f2bf(fb.x) | (f2bf(fb.y) << 16);
            wv.w = f2bf(fb.z) | (f2bf(fb.w) << 16);
            *(uint4*)&Ap[kg][row][0] = wv;
        }
        {
            const float* src = &F[(size_t)(b*PNUM + q0 + row)*64 + kg*8];
            float4 fa = *(const float4*)src, fb = *(const float4*)(src + 4);
            uint4 wv;
            wv.x = f2bf(fa.x) | (f2bf(fa.y) << 16);
            wv.y = f2bf(fa.z) | (f2bf(fa.w) << 16);
            wv.z = f2bf(fb.x) | (f2bf(fb.y) << 16);
            wv.w = f2bf(fb.z) | (f2bf(fb.w) << 16);
            *(uint4*)&Aq[kg][row][0] = wv;
        }
    }
    __syncthreads();
    f32x4 acc[4][4] = {};
    #pragma unroll
    for (int ks = 0; ks < 2; ks++) {
        short8v af[4], bf[4];
        #pragma unroll
        for (int mf = 0; mf < 4; mf++)
            af[mf] = *(const short8v*)&Ap[ks*4 + (lane >> 4)][wm + mf*16 + (lane & 15)][0];
        #pragma unroll
        for (int nf = 0; nf < 4; nf++)
            bf[nf] = *(const short8v*)&Aq[ks*4 + (lane >> 4)][wn + nf*16 + (lane & 15)][0];
        #pragma unroll
        for (int mf = 0; mf < 4; mf++)
            #pragma unroll
            for (int nf = 0; nf < 4; nf++)
                acc[mf][nf] = __builtin_amdgcn_mfma_f32_16x16x32_bf16(af[mf], bf[nf], acc[mf][nf], 0, 0, 0);
    }
    int crow = (lane >> 4)*4;
    int ccol = lane & 15;
    #pragma unroll
    for (int mf = 0; mf < 4; mf++) {
        #pragma unroll
        for (int r = 0; r < 4; r++) {
            int row = wm + mf*16 + crow + r;
            float spv = sp[row];
            size_t base = (size_t)(b*PNUM + p0 + row)*PNUM + q0;
            #pragma unroll
            for (int nf = 0; nf < 4; nf++) {
                int col = wn + nf*16 + ccol;
                float d = spv + sq[col] - 2.0f*acc[mf][nf][r];
                Dk[base + col] = (ushort_t)(mono_key(d) >> 16);
            }
        }
    }
}

// ---------- candidate select: binary search threshold on u16 keys; no atomics ----------
__global__ __launch_bounds__(256) void k_topk(const ushort_t* __restrict__ Dk,
                                              int* __restrict__ cand, int* __restrict__ ccnt) {
    __shared__ int red[4];
    __shared__ int wbase[4];
    int n = blockIdx.x, t = threadIdx.x, lane = t & 63, w = t >> 6;
    uint4 wv = *(const uint4*)(Dk + (size_t)n*PNUM + t*8);
    int ks[8];
    ks[0] = wv.x & 0xffff; ks[1] = wv.x >> 16;
    ks[2] = wv.y & 0xffff; ks[3] = wv.y >> 16;
    ks[4] = wv.z & 0xffff; ks[5] = wv.z >> 16;
    ks[6] = wv.w & 0xffff; ks[7] = wv.w >> 16;
    int lo = 0, hi = 65535;
    while (lo < hi) {
        int mid = (lo + hi) >> 1;
        int c = 0;
        #pragma unroll
        for (int e = 0; e < 8; e++) c += (ks[e] <= mid);
        #pragma unroll
        for (int o = 32; o >= 1; o >>= 1) c += __shfl_xor(c, o, 64);
        if (lane == 0) red[w] = c;
        __syncthreads();
        int tot = red[0] + red[1] + red[2] + red[3];
        __syncthreads();
        if (tot >= KSEL) hi = mid; else lo = mid + 1;
    }
    int P = lo;
    int lc = 0;
    #pragma unroll
    for (int e = 0; e < 8; e++) lc += (ks[e] <= P);
    int pre = lc;
    #pragma unroll
    for (int o = 1; o < 64; o <<= 1) { int vv = __shfl_up(pre, o, 64); if (lane >= o) pre += vv; }
    int excl = pre - lc;
    if (lane == 63) red[w] = pre;
    __syncthreads();
    if (t == 0) {
        int s0 = 0;
        #pragma unroll
        for (int i = 0; i < 4; i++) { wbase[i] = s0; s0 += red[i]; }
        ccnt[n] = (s0 < KCAP) ? s0 : KCAP;
    }
    __syncthreads();
    int base = wbase[w] + excl;
    #pragma unroll
    for (int e = 0; e < 8; e++) {
        if (ks[e] <= P) {
            if (base < KCAP) cand[(size_t)n*KCAP + base] = t*8 + e;
            base++;
        }
    }
}

// ---------- refine: f64 distances + all-pairs rank ----------
template<int C>
__global__ __launch_bounds__(256) void k_refine(const float* __restrict__ F,
                                                const int* __restrict__ cand,
                                                const int* __restrict__ ccnt,
                                                int* __restrict__ idx) {
    int t = threadIdx.x;
    int lane = t & 63;
    int row = blockIdx.x*4 + (t >> 6);
    int b = row >> 11;
    const float* fp = F + (size_t)row*C;
    int cnt = ccnt[row];
    bool act = lane < cnt;
    int q = act ? cand[(size_t)row*KCAP + lane] : (lane | 0x40000000);
    const float* fq = F + (size_t)(b*PNUM + (act ? q : 0))*C;
    double d = 1e300;
    if (act) {
        d = 0.0;
        if (C == 64) {
            #pragma unroll
            for (int c4 = 0; c4 < C/4; c4++) {
                float4 a = ((const float4*)fp)[c4];
                float4 bb = ((const float4*)fq)[c4];
                double d0 = (double)a.x - (double)bb.x;
                double d1 = (double)a.y - (double)bb.y;
                double d2 = (double)a.z - (double)bb.z;
                double d3 = (double)a.w - (double)bb.w;
                d += d0*d0 + d1*d1 + d2*d2 + d3*d3;
            }
        } else {
            #pragma unroll
            for (int c = 0; c < C; c++) {
                double df = (double)fp[c] - (double)fq[c];
                d += df*df;
            }
        }
    }
    int rank = 0;
    #pragma unroll 16
    for (int l = 0; l < 64; l++) {
        double dl = lane_bcast64(d, l);
        int ql = __builtin_amdgcn_readlane(q, l);
        rank += (dl < d) || (dl == d && ql < q);
    }
    if (act && rank < KNN) idx[(size_t)row*KNN + rank] = q;
}

// ---------- fused u/v GEMM: u = F@(W0a-W0b)+b0, v = F@W0b ----------
template<int C>
__global__ __launch_bounds__(256) void k_uv(const float* __restrict__ F,
                                            const float* __restrict__ W0,
                                            const float* __restrict__ b0,
                                            float* __restrict__ u, float* __restrict__ v) {
    __shared__ float As[64][17];
    __shared__ float Wa[16][64];
    __shared__ float Wb[16][64];
    int m0 = blockIdx.x*64;
    int t = threadIdx.x;
    int cb = (t & 15)*4, rb = (t >> 4)*4;
    float aU[4][4] = {}, aV[4][4] = {};
    for (int k0 = 0; k0 < C; k0 += 16) {
        #pragma unroll
        for (int j = 0; j < 4; j++) {
            int e = t + 256*j;
            int r = e >> 4, c = e & 15;
            As[r][c] = (k0 + c < C) ? F[(size_t)(m0 + r)*C + k0 + c] : 0.f;
        }
        {
            int r = t >> 4, c4 = (t & 15)*4;
            bool ok = (k0 + r < C);
            float4 wa = ok ? *(const float4*)&W0[(size_t)(k0 + r)*64 + c4] : make_float4(0,0,0,0);
            float4 wb = ok ? *(const float4*)&W0[(size_t)(C + k0 + r)*64 + c4] : make_float4(0,0,0,0);
            *(float4*)&Wa[r][c4] = wa;
            *(float4*)&Wb[r][c4] = wb;
        }
        __syncthreads();
        #pragma unroll
        for (int kk = 0; kk < 16; kk++) {
            float a[4];
            #pragma unroll
            for (int i = 0; i < 4; i++) a[i] = As[rb + i][kk];
            float4 wa4 = *(const float4*)&Wa[kk][cb];
            float4 wb4 = *(const float4*)&Wb[kk][cb];
            float wa[4] = {wa4.x, wa4.y, wa4.z, wa4.w};
            float wb[4] = {wb4.x, wb4.y, wb4.z, wb4.w};
            #pragma unroll
            for (int i = 0; i < 4; i++)
                #pragma unroll
                for (int j = 0; j < 4; j++) {
                    aU[i][j] = fmaf(a[i], wa[j] - wb[j], aU[i][j]);
                    aV[i][j] = fmaf(a[i], wb[j], aV[i][j]);
                }
        }
        __syncthreads();
    }
    #pragma unroll
    for (int i = 0; i < 4; i++) {
        int row = m0 + rb + i;
        #pragma unroll
        for (int j = 0; j < 4; j++) {
            int col = cb + j;
            u[(size_t)row*64 + col] = aU[i][j] + b0[col];
            v[(size_t)row*64 + col] = aV[i][j];
        }
    }
}

// ---------- 64-wide tiled f32 GEMM (final ho layer) ----------
template<int RELU>
__global__ __launch_bounds__(256) void k_gemm(const float* __restrict__ A,
                                              const float* __restrict__ W,
                                              const float* __restrict__ bias,
                                              float* __restrict__ out,
                                              int M, int Kd, int Nd) {
    __shared__ float As[64][17];
    __shared__ float Bs[16][64];
    int m0 = blockIdx.x*64, n0 = blockIdx.y*64;
    int t = threadIdx.x;
    int cb = (t & 15)*4, rb = (t >> 4)*4;
    float acc[4][4] = {};
    for (int k0 = 0; k0 < Kd; k0 += 16) {
        #pragma unroll
        for (int j = 0; j < 4; j++) {
            int e = t + 256*j;
            int r = e >> 4, c = e & 15;
            As[r][c] = (k0 + c < Kd) ? A[(size_t)(m0 + r)*Kd + k0 + c] : 0.f;
        }
        #pragma unroll
        for (int j = 0; j < 4; j++) {
            int e = t + 256*j;
            int r = e >> 6, c = e & 63;
            Bs[r][c] = (k0 + r < Kd && n0 + c < Nd) ? W[(size_t)(k0 + r)*Nd + n0 + c] : 0.f;
        }
        __syncthreads();
        #pragma unroll
        for (int kk = 0; kk < 16; kk++) {
            float a[4];
            #pragma unroll
            for (int i = 0; i < 4; i++) a[i] = As[rb + i][kk];
            float4 w4 = *(const float4*)&Bs[kk][cb];
            float w[4] = {w4.x, w4.y, w4.z, w4.w};
            #pragma unroll
            for (int i = 0; i < 4; i++)
                #pragma unroll
                for (int j = 0; j < 4; j++) acc[i][j] += a[i]*w[j];
        }
        __syncthreads();
    }
    #pragma unroll
    for (int i = 0; i < 4; i++) {
        int row = m0 + rb + i;
        #pragma unroll
        for (int j = 0; j < 4; j++) {
            int col = n0 + cb + j;
            if (col < Nd) {
                float v = acc[i][j] + (bias ? bias[col] : 0.f);
                if (RELU) v = fmaxf(v, 0.f);
                out[(size_t)row*Nd + col] = v;
            }
        }
    }
}

// ---------- pack f32 weights [Kd][Nd] -> bf16 fragment layout [(Kd/8)][Nd][8] ----------
__global__ void k_pack(const float* __restrict__ W, ushort_t* __restrict__ Wpk,
                       int Kd, int Nd) {
    int cell = blockIdx.x*256 + threadIdx.x;
    int ncell = (Kd >> 3)*Nd;
    if (cell >= ncell) return;
    int kg = cell / Nd, n = cell - kg*Nd;
    unsigned b[8];
    #pragma unroll
    for (int j = 0; j < 8; j++) b[j] = f2bf(W[(size_t)(kg*8 + j)*Nd + n]);
    uint4 wv;
    wv.x = b[0] | (b[1] << 16); wv.y = b[2] | (b[3] << 16);
    wv.z = b[4] | (b[5] << 16); wv.w = b[6] | (b[7] << 16);
    *(uint4*)&Wpk[(size_t)cell*8] = wv;
}

// ---------- bf16 MFMA GEMM: 128x128 tile, 4 waves (2x2 of 64x64), f32 out ----------
template<int CONCAT, int RELU>
__global__ __launch_bounds__(256) void k_mgemm(const float* __restrict__ A,
                                               const float* __restrict__ A2,
                                               const float* __restrict__ A3,
                                               const ushort_t* __restrict__ Wpk,
                                               const float* __restrict__ bias,
                                               float* __restrict__ out,
                                               int Kd, int Nd) {
    __shared__ ushort_t Al[4][128][8];
    __shared__ ushort_t Bl[4][128][8];
    int m0 = blockIdx.x*128, n0 = blockIdx.y*128;
    int t = threadIdx.x, lane = t & 63, w = t >> 6;
    int wm = (w >> 1)*64, wn = (w & 1)*64;
    f32x4 acc[4][4] = {};
    int arow = t >> 2, akg = t & 3;
    for (int k0 = 0; k0 < Kd; k0 += 32) {
        #pragma unroll
        for (int i = 0; i < 2; i++) {
            int row = arow + 64*i;
            int kb = k0 + akg*8;
            const float* src;
            if (CONCAT) {
                const float* s0 = (kb < 64) ? A : (kb < 128) ? A2 : A3;
                src = s0 + (size_t)(m0 + row)*64 + (kb & 63);
            } else {
                src = A + (size_t)(m0 + row)*Kd + kb;
            }
            float4 fa = *(const float4*)src;
            float4 fb = *(const float4*)(src + 4);
            uint4 wv;
            wv.x = f2bf(fa.x) | (f2bf(fa.y) << 16);
            wv.y = f2bf(fa.z) | (f2bf(fa.w) << 16);
            wv.z = f2bf(fb.x) | (f2bf(fb.y) << 16);
            wv.w = f2bf(fb.z) | (f2bf(fb.w) << 16);
            *(uint4*)&Al[akg][row][0] = wv;
        }
        #pragma unroll
        for (int i = 0; i < 2; i++) {
            int cell = t + 256*i;
            int kg = cell >> 7, col = cell & 127;
            *(uint4*)&Bl[kg][col][0] =
                *(const uint4*)&Wpk[((size_t)(k0/8 + kg)*Nd + n0 + col)*8];
        }
        __syncthreads();
        short8v af[4], bf[4];
        #pragma unroll
        for (int mf = 0; mf < 4; mf++)
            af[mf] = *(const short8v*)&Al[lane >> 4][wm + mf*16 + (lane & 15)][0];
        #pragma unroll
        for (int nf = 0; nf < 4; nf++)
            bf[nf] = *(const short8v*)&Bl[lane >> 4][wn + nf*16 + (lane & 15)][0];
        #pragma unroll
        for (int mf = 0; mf < 4; mf++)
            #pragma unroll
            for (int nf = 0; nf < 4; nf++)
                acc[mf][nf] = __builtin_amdgcn_mfma_f32_16x16x32_bf16(af[mf], bf[nf], acc[mf][nf], 0, 0, 0);
        __syncthreads();
    }
    int crow = (lane >> 4)*4;
    int ccol = lane & 15;
    #pragma unroll
    for (int nf = 0; nf < 4; nf++) {
        int col = n0 + wn + nf*16 + ccol;
        float bv = bias[col];
        #pragma unroll
        for (int mf = 0; mf < 4; mf++) {
            #pragma unroll
            for (int r = 0; r < 4; r++) {
                int row = m0 + wm + mf*16 + crow + r;
                float vv = acc[mf][nf][r] + bv;
                if (RELU) vv = fmaxf(vv, 0.f);
                out[(size_t)row*Nd + col] = vv;
            }
        }
    }
}

// ---------- stats of relu(u_p + v_q) over all edges (float4 vectorized) ----------
__global__ __launch_bounds__(256) void k_e1stats(const float* __restrict__ u,
                                                 const float* __restrict__ v,
                                                 const int* __restrict__ idx,
                                                 float* __restrict__ psum, float* __restrict__ psq) {
    int t = threadIdx.x;
    float s0 = 0.f, s1 = 0.f, s2 = 0.f, s3 = 0.f;
    float q0 = 0.f, q1 = 0.f, q2 = 0.f, q3 = 0.f;
    const int stride = 3840*256;
    int i = blockIdx.x*256 + t;
    int c4 = (i & 15)*4;
    #pragma unroll 1
    for (int j = 0; j < 8; j++, i += stride) {
        int edge = i >> 4;
        int p = edge / KNN;
        int q = idx[edge];
        int b = p >> 11;
        float4 uv = *(const float4*)&u[(size_t)p*64 + c4];
        float4 vv = *(const float4*)&v[(size_t)(b*PNUM + q)*64 + c4];
        float h0 = fmaxf(uv.x + vv.x, 0.f);
        float h1 = fmaxf(uv.y + vv.y, 0.f);
        float h2 = fmaxf(uv.z + vv.z, 0.f);
        float h3 = fmaxf(uv.w + vv.w, 0.f);
        s0 += h0; s1 += h1; s2 += h2; s3 += h3;
        q0 = fmaf(h0, h0, q0); q1 = fmaf(h1, h1, q1);
        q2 = fmaf(h2, h2, q2); q3 = fmaf(h3, h3, q3);
    }
    __shared__ float rs[16][16][4];
    __shared__ float rq[16][16][4];
    int slot = t >> 4, g = t & 15;
    rs[slot][g][0] = s0; rs[slot][g][1] = s1; rs[slot][g][2] = s2; rs[slot][g][3] = s3;
    rq[slot][g][0] = q0; rq[slot][g][1] = q1; rq[slot][g][2] = q2; rq[slot][g][3] = q3;
    __syncthreads();
    if (t < 64) {
        int gg = t >> 2, comp = t & 3;
        float ss = 0.f, qq = 0.f;
        #pragma unroll
        for (int sl = 0; sl < 16; sl++) { ss += rs[sl][gg][comp]; qq += rq[sl][gg][comp]; }
        psum[(size_t)blockIdx.x*64 + t] = ss;
        psq [(size_t)blockIdx.x*64 + t] = qq;
    }
}

// ---------- finalize BN stats ----------
__global__ void k_statsfin(const float* __restrict__ psum, const float* __restrict__ psq,
                           int npart, int C, float invM,
                           const float* __restrict__ g, const float* __restrict__ be,
                           float* __restrict__ scale, float* __restrict__ shift) {
    int c = blockIdx.x, t = threadIdx.x;
    float s = 0.f, q = 0.f;
    for (int i = t; i < npart; i += 256) {
        s += psum[(size_t)i*C + c];
        q += psq [(size_t)i*C + c];
    }
    __shared__ float rs[256], rq[256];
    rs[t] = s; rq[t] = q; __syncthreads();
    for (int off = 128; off >= 1; off >>= 1) {
        if (t < off) { rs[t] += rs[t+off]; rq[t] += rq[t+off]; }
        __syncthreads();
    }
    if (t == 0) {
        float m   = rs[0]*invM;
        float var = rq[0]*invM - m*m;
        float inv = rsqrtf(var + EPSF);
        float sc  = g[c]*inv;
        scale[c] = sc;
        shift[c] = be[c] - m*sc;
    }
}

// ---------- fold BN affine into next linear ----------
__global__ void k_fold(const float* __restrict__ W, const float* __restrict__ b,
                       const float* __restrict__ scale, const float* __restrict__ shift,
                       float* __restrict__ Wp, float* __restrict__ bp, int Cin, int Cout) {
    int co = blockIdx.x, t = threadIdx.x;
    float acc = 0.f;
    for (int ci = t; ci < Cin; ci += 256) {
        float w = W[(size_t)ci*Cout + co];
        Wp[(size_t)ci*Cout + co] = scale[ci]*w;
        acc += shift[ci]*w;
    }
    __shared__ float r[256];
    r[t] = acc; __syncthreads();
    for (int off = 128; off >= 1; off >>= 1) { if (t < off) r[t] += r[t+off]; __syncthreads(); }
    if (t == 0) bp[co] = b[co] + r[0];
}

// ---------- edge layer 1 (f32, kNN-feeding convs): wave-per-point broadcast matvec ----------
__global__ __launch_bounds__(256, 4) void k_e2(const float* __restrict__ u, const float* __restrict__ v,
                                               const int* __restrict__ idx,
                                               const float* __restrict__ W1p, const float* __restrict__ b1p,
                                               float* __restrict__ pmax, float* __restrict__ pmin,
                                               float* __restrict__ psum, float* __restrict__ psq) {
    __shared__ float hbuf[4][64];
    int t = threadIdx.x, lane = t & 63, w = t >> 6;
    int p = blockIdx.x*4 + w;
    int b = p >> 11;
    float wcol[64];
    #pragma unroll
    for (int c = 0; c < 64; c++) wcol[c] = W1p[c*64 + lane];
    #pragma unroll
    for (int c = 0; c < 64; c++) asm volatile("" : "+v"(wcol[c]));
    float ureg = u[(size_t)p*64 + lane];
    float bias = b1p[lane];
    const int* myidx = idx + (size_t)p*KNN;
    const float* vb = v + (size_t)b*PNUM*64;
    float mx = -1e30f, mn = 1e30f, sm = 0.f, sq = 0.f;
    int q = myidx[0];
    float vk = vb[(size_t)q*64 + lane];
    #pragma unroll 1
    for (int k = 0; k < KNN; k++) {
        float h = fmaxf(ureg + vk, 0.f);
        hbuf[w][lane] = h;
        if (k + 1 < KNN) {
            int qn = myidx[k + 1];
            vk = vb[(size_t)qn*64 + lane];
        }
        float a0 = 0.f, a1 = 0.f, a2 = 0.f, a3 = 0.f;
        #pragma unroll
        for (int c = 0; c < 64; c += 4) {
            float4 h4 = *(const float4*)&hbuf[w][c];
            a0 = fmaf(h4.x, wcol[c    ], a0);
            a1 = fmaf(h4.y, wcol[c + 1], a1);
            a2 = fmaf(h4.z, wcol[c + 2], a2);
            a3 = fmaf(h4.w, wcol[c + 3], a3);
        }
        float o = fmaxf((a0 + a1) + (a2 + a3) + bias, 0.f);
        mx = fmaxf(mx, o);
        mn = fminf(mn, o);
        sm += o;
        sq = fmaf(o, o, sq);
    }
    pmax[(size_t)p*64 + lane] = mx;
    pmin[(size_t)p*64 + lane] = mn;
    psum[(size_t)p*64 + lane] = sm;
    psq [(size_t)p*64 + lane] = sq;
}

// ---------- edge layer 1 (bf16 MFMA, conv3 only — x3 feeds no kNN) ----------
__global__ __launch_bounds__(256) void k_e2m(const float* __restrict__ u, const float* __restrict__ v,
                                             const int* __restrict__ idx,
                                             const ushort_t* __restrict__ Wpk, const float* __restrict__ b1p,
                                             float* __restrict__ pmax, float* __restrict__ pmin,
                                             float* __restrict__ psum, float* __restrict__ psq) {
    __shared__ int idxs[4][32];
    int t = threadIdx.x, lane = t & 63, w = t >> 6;
    int p = blockIdx.x*4 + w;
    int b = p >> 11;
    if (lane < 32) idxs[w][lane] = (lane < KNN) ? idx[(size_t)p*KNN + lane] : -1;
    const float* vb = v + (size_t)b*PNUM*64;
    int oct = lane >> 4;
    int col16 = lane & 15;
    float uo[2][8];
    #pragma unroll
    for (int kb = 0; kb < 2; kb++) {
        const float* up = &u[(size_t)p*64 + kb*32 + oct*8];
        float4 a = *(const float4*)up;
        float4 bq = *(const float4*)(up + 4);
        uo[kb][0]=a.x; uo[kb][1]=a.y; uo[kb][2]=a.z; uo[kb][3]=a.w;
        uo[kb][4]=bq.x; uo[kb][5]=bq.y; uo[kb][6]=bq.z; uo[kb][7]=bq.w;
    }
    short8v af[2][2];
    #pragma unroll
    for (int mf = 0; mf < 2; mf++) {
        int r = mf*16 + col16;
        int q = idxs[w][r];
        #pragma unroll
        for (int kb = 0; kb < 2; kb++) {
            uint4 wv = make_uint4(0u, 0u, 0u, 0u);
            if (q >= 0) {
                const float* vp = &vb[(size_t)q*64 + kb*32 + oct*8];
                float4 va = *(const float4*)vp;
                float4 vbq = *(const float4*)(vp + 4);
                float h0 = fmaxf(uo[kb][0] + va.x,  0.f);
                float h1 = fmaxf(uo[kb][1] + va.y,  0.f);
                float h2 = fmaxf(uo[kb][2] + va.z,  0.f);
                float h3 = fmaxf(uo[kb][3] + va.w,  0.f);
                float h4 = fmaxf(uo[kb][4] + vbq.x, 0.f);
                float h5 = fmaxf(uo[kb][5] + vbq.y, 0.f);
                float h6 = fmaxf(uo[kb][6] + vbq.z, 0.f);
                float h7 = fmaxf(uo[kb][7] + vbq.w, 0.f);
                wv.x = f2bf(h0) | (f2bf(h1) << 16);
                wv.y = f2bf(h2) | (f2bf(h3) << 16);
                wv.z = f2bf(h4) | (f2bf(h5) << 16);
                wv.w = f2bf(h6) | (f2bf(h7) << 16);
            }
            union { uint4 ui; short8v sv; } cvt; cvt.ui = wv;
            af[mf][kb] = cvt.sv;
        }
    }
    short8v bf[2][4];
    #pragma unroll
    for (int kb = 0; kb < 2; kb++)
        #pragma unroll
        for (int nf = 0; nf < 4; nf++)
            bf[kb][nf] = *(const short8v*)&Wpk[((size_t)(kb*4 + oct)*64 + nf*16 + col16)*8];
    f32x4 acc[2][4] = {};
    #pragma unroll
    for (int kb = 0; kb < 2; kb++)
        #pragma unroll
        for (int mf = 0; mf < 2; mf++)
            #pragma unroll
            for (int nf = 0; nf < 4; nf++)
                acc[mf][nf] = __builtin_amdgcn_mfma_f32_16x16x32_bf16(af[mf][kb], bf[kb][nf], acc[mf][nf], 0, 0, 0);
    #pragma unroll
    for (int nf = 0; nf < 4; nf++) {
        float bj = b1p[nf*16 + col16];
        float mx = -1e30f, mn = 1e30f, sm = 0.f, sq = 0.f;
        #pragma unroll
        for (int mf = 0; mf < 2; mf++)
            #pragma unroll
            for (int r4 = 0; r4 < 4; r4++) {
                int row = mf*16 + oct*4 + r4;
                if (row < KNN) {
                    float o = fmaxf(acc[mf][nf][r4] + bj, 0.f);
                    mx = fmaxf(mx, o);
                    mn = fminf(mn, o);
                    sm += o;
                    sq = fmaf(o, o, sq);
                }
            }
        mx = fmaxf(mx, __shfl_xor(mx, 16, 64));
        mn = fminf(mn, __shfl_xor(mn, 16, 64));
        sm += __shfl_xor(sm, 16, 64);
        sq += __shfl_xor(sq, 16, 64);
        mx = fmaxf(mx, __shfl_xor(mx, 32, 64));
        mn = fminf(mn, __shfl_xor(mn, 32, 64));
        sm += __shfl_xor(sm, 32, 64);
        sq += __shfl_xor(sq, 32, 64);
        if (oct == 0) {
            int col = nf*16 + col16;
            pmax[(size_t)p*64 + col] = mx;
            pmin[(size_t)p*64 + col] = mn;
            psum[(size_t)p*64 + col] = sm;
            psq [(size_t)p*64 + col] = sq;
        }
    }
}

// ---------- BN1 applied after pooling (max if scale>=0 else min) ----------
__global__ void k_applypool(const float* __restrict__ pmax, const float* __restrict__ pmin,
                            const float* __restrict__ scale, const float* __restrict__ shift,
                            float* __restrict__ out) {
    int i = blockIdx.x*256 + threadIdx.x;
    int c = i & 63;
    float sc = scale[c];
    float pooled = (sc >= 0.f) ? pmax[i] : pmin[i];
    out[i] = sc*pooled + shift[c];
}

// ---------- per-column partial sums over 64-row blocks ----------
__global__ void k_colstats(const float* __restrict__ Hbuf, float* __restrict__ psum,
                           float* __restrict__ psq, int Cout) {
    int m0 = blockIdx.x*64, c0 = blockIdx.y*64;
    int t = threadIdx.x;
    int c = t & 63, rg = t >> 6;
    float s = 0.f, q = 0.f;
    #pragma unroll 4
    for (int r = 0; r < 16; r++) {
        float hv = Hbuf[(size_t)(m0 + rg*16 + r)*Cout + c0 + c];
        s += hv; q += hv*hv;
    }
    __shared__ float rs[256], rq[256];
    rs[t] = s; rq[t] = q; __syncthreads();
    if (t < 128) { rs[t] += rs[t+128]; rq[t] += rq[t+128]; }
    __syncthreads();
    if (t < 64) {
        rs[t] += rs[t+64]; rq[t] += rq[t+64];
        psum[(size_t)blockIdx.x*Cout + c0 + t] = rs[t];
        psq [(size_t)blockIdx.x*Cout + c0 + t] = rq[t];
    }
}

// ---------- log_softmax over 50 cols, one wave per row ----------
__global__ void k_logsoftmax(const float* __restrict__ logits, float* __restrict__ out) {
    int t = threadIdx.x;
    int n = blockIdx.x*4 + (t >> 6);
    int l = t & 63;
    float z = (l < 50) ? logits[(size_t)n*50 + l] : -INFINITY;
    float mx = z;
    #pragma unroll
    for (int off = 32; off >= 1; off >>= 1) mx = fmaxf(mx, __shfl_xor(mx, off, 64));
    float ex = (l < 50) ? expf(z - mx) : 0.f;
    float sm = ex;
    #pragma unroll
    for (int off = 32; off >= 1; off >>= 1) sm += __shfl_xor(sm, off, 64);
    float lse = mx + logf(sm);
    if (l < 50) out[(size_t)n*50 + l] = z - lse;
}

extern "C" void kernel_launch(void* const* d_in, const int* in_sizes, int n_in,
                              void* d_out, int out_size, void* d_ws, size_t ws_size,
                              hipStream_t stream) {
    (void)in_sizes; (void)n_in; (void)out_size;
    const float* x   = (const float*)d_in[0];
    const float* pos = (const float*)d_in[1];
    const float* prm[38];
    for (int i = 0; i < 38; i++) prm[i] = (const float*)d_in[3 + i];
    // prm: c1[0..7] c2[8..15] c3[16..23] l1[24..27] h0[28..31] h1[32..35] ho[36..37]

    float* ws = (float*)d_ws;
    size_t off = 0;
    auto alloc = [&](size_t cnt) { float* p = ws + off; off += (cnt + 63) & ~((size_t)63); return p; };
    float* f0   = alloc((size_t)NPT*6);
    float* s    = alloc(NPT);
    float* x1   = alloc((size_t)NPT*64);
    float* x2   = alloc((size_t)NPT*64);
    float* x3   = alloc((size_t)NPT*64);
    float* u    = alloc((size_t)NPT*64);
    float* v    = alloc((size_t)NPT*64);
    float* pmax = alloc((size_t)NPT*64);
    float* pmin = alloc((size_t)NPT*64);
    int*   idx  = (int*)alloc((size_t)NPT*KNN);
    int*   ccnt = (int*)alloc(NPT);
    float* W1p  = alloc(64*64);
    float* b1p  = alloc(64);
    float* scaleA = alloc(1024);
    float* shiftA = alloc(1024);
    float* Wp   = alloc(1024*256);
    float* bp   = alloc(1024);
    ushort_t* Wpk1 = (ushort_t*)alloc(98304);    // l1 packed weights (192*1024 bf16)
    ushort_t* Wpk2 = (ushort_t*)alloc(131072);   // h0/h1 + conv3-e2 packed weights
    float* psum = alloc((size_t)NPT*64);
    float* psq  = alloc((size_t)NPT*64);
    float* big  = alloc((size_t)BNUM*PNUM*PNUM);   // shared: Dk (u16), then head activations
    if (off*sizeof(float) > ws_size) return;       // insufficient workspace -> leave poisoned

    int* cand = (int*)psum;
    ushort_t* Dk = (ushort_t*)big;

    auto conv = [&](const float* F, int C, const float* const* pp, float* xout, bool mfma_e2) {
        if (C == 6) {
            k_dist<6><<<dim3(16,16,8), 256, 0, stream>>>(F, Dk);
        } else {
            k_snorm<64><<<NPT/256, 256, 0, stream>>>(F, s);
            k_mdist<<<dim3(16,16,8), 256, 0, stream>>>(F, s, Dk);
        }
        k_topk<<<NPT, 256, 0, stream>>>(Dk, cand, ccnt);
        if (C == 6) k_refine<6><<<NPT/4, 256, 0, stream>>>(F, cand, ccnt, idx);
        else        k_refine<64><<<NPT/4, 256, 0, stream>>>(F, cand, ccnt, idx);
        if (C == 6) k_uv<6><<<NPT/64, 256, 0, stream>>>(F, pp[0], pp[1], u, v);
        else        k_uv<64><<<NPT/64, 256, 0, stream>>>(F, pp[0], pp[1], u, v);
        k_e1stats<<<3840, 256, 0, stream>>>(u, v, idx, psum, psq);
        k_statsfin<<<64, 256, 0, stream>>>(psum, psq, 3840, 64, 1.f/((float)NPT*KNN),
                                           pp[2], pp[3], scaleA, shiftA);
        k_fold<<<64, 256, 0, stream>>>(pp[4], pp[5], scaleA, shiftA, W1p, b1p, 64, 64);
        if (mfma_e2) {
            k_pack<<<2, 256, 0, stream>>>(W1p, Wpk2, 64, 64);
            k_e2m<<<NPT/4, 256, 0, stream>>>(u, v, idx, Wpk2, b1p, pmax, pmin, psum, psq);
        } else {
            k_e2<<<NPT/4, 256, 0, stream>>>(u, v, idx, W1p, b1p, pmax, pmin, psum, psq);
        }
        k_statsfin<<<64, 256, 0, stream>>>(psum, psq, NPT, 64, 1.f/((float)NPT*KNN),
                                           pp[6], pp[7], scaleA, shiftA);
        k_applypool<<<NPT*64/256, 256, 0, stream>>>(pmax, pmin, scaleA, shiftA, xout);
    };

    k_concat6<<<NPT*6/256, 256, 0, stream>>>(x, pos, f0);
    k_pack<<<96, 256, 0, stream>>>(prm[24], Wpk1, 192, 1024);   // l1 weights
    conv(f0, 6,  &prm[0],  x1, false);   // x1 feeds kNN2 -> f32 e2
    conv(x1, 64, &prm[8],  x2, false);   // x2 feeds kNN3 -> f32 e2
    conv(x2, 64, &prm[16], x3, true);    // x3 head-only -> bf16 MFMA e2

    float* Hb1    = big + 3145728;
    float* Hb2    = big + 19922944;
    float* Hb3    = big + 24117248;
    float* logits = big + 26214400;

    k_mgemm<1,1><<<dim3(NPT/128, 8), 256, 0, stream>>>(x1, x2, x3, Wpk1, prm[25], Hb1, 192, 1024);
    k_colstats<<<dim3(NPT/64, 16), 256, 0, stream>>>(Hb1, psum, psq, 1024);
    k_statsfin<<<1024, 256, 0, stream>>>(psum, psq, NPT/64, 1024, 1.f/(float)NPT,
                                         prm[26], prm[27], scaleA, shiftA);
    k_fold<<<256, 256, 0, stream>>>(prm[28], prm[29], scaleA, shiftA, Wp, bp, 1024, 256);
    k_pack<<<128, 256, 0, stream>>>(Wp, Wpk2, 1024, 256);
    k_mgemm<0,1><<<dim3(NPT/128, 2), 256, 0, stream>>>(Hb1, nullptr, nullptr, Wpk2, bp, Hb2, 1024, 256);
    k_colstats<<<dim3(NPT/64, 4), 256, 0, stream>>>(Hb2, psum, psq, 256);
    k_statsfin<<<256, 256, 0, stream>>>(psum, psq, NPT/64, 256, 1.f/(float)NPT,
                                        prm[30], prm[31], scaleA, shiftA);
    k_fold<<<128, 256, 0, stream>>>(prm[32], prm[33], scaleA, shiftA, Wp, bp, 256, 128);
    k_pack<<<16, 256, 0, stream>>>(Wp, Wpk2, 256, 128);
    k_mgemm<0,1><<<dim3(NPT/128, 1), 256, 0, stream>>>(Hb2, nullptr, nullptr, Wpk2, bp, Hb3, 256, 128);
    k_colstats<<<dim3(NPT/64, 2), 256, 0, stream>>>(Hb3, psum, psq, 128);
    k_statsfin<<<128, 256, 0, stream>>>(psum, psq, NPT/64, 128, 1.f/(float)NPT,
                                        prm[34], prm[35], scaleA, shiftA);
    k_fold<<<50, 256, 0, stream>>>(prm[36], prm[37], scaleA, shiftA, Wp, bp, 128, 50);
    k_gemm<0><<<dim3(NPT/64, 1), 256, 0, stream>>>(Hb3, Wp, bp, logits, NPT, 128, 50);
    k_logsoftmax<<<NPT/4, 256, 0, stream>>>(logits, (float*)d_out);
}